// Round 12
// baseline (111.919 us; speedup 1.0000x reference)
//
#include <hip/hip_runtime.h>
#include <hip/hip_bf16.h>

#define A_N 8
#define C_N 256
#define H_N 80
#define W_N 108
#define P_N (H_N * W_N)      // 8640
#define P4_N (P_N / 4)       // 2160 float4 columns per plane
#define PG4  (A_N * P4_N)    // 17280 global float4 columns (exact 270*64)
#define O_N 7
#define MH 256
#define MW 256
#define OUT_HW 256

__device__ __forceinline__ float sigmoidf_(float zv) {
    return 1.0f / (1.0f + __expf(-zv));
}

// ---------------------------------------------------------------------------
// Fused resize + conv. Grid 270 x 256 thr (4 waves), zero tail.
// Wave-PRIVATE pipelined staging: each wave owns 16KB LDS (4 slots x 4ch x
// 1KB), stages its 64-channel quarter via global_load_lds in 16 batches of 4,
// counted s_waitcnt vmcnt(12) -> 3 batches (12KB/wave, 48KB/CU) always in
// flight. NO barriers in the loop (r11 lesson: barrier-locked waves at
// 1 block/CU drain the whole CU every step). Cross-wave LDS reduce at end.
// ---------------------------------------------------------------------------
__global__ void k_conv(const float* __restrict__ x, const float* __restrict__ masks,
                       const float* __restrict__ w, const float* __restrict__ b,
                       float* __restrict__ z, float* __restrict__ ssolo)
{
    __shared__ float s_x[16384];   // 4 waves x 4 slots x 4 ch x 256 floats (64KB)
    __shared__ float s_w[2048];    // w transposed [c][8]
    __shared__ float s_cm[256];    // resized mask for this block's 256 px

    const int tid  = threadIdx.x;
    const int lane = tid & 63;
    const int wid  = tid >> 6;

    // ---- prologue A: stage w -> LDS as [c][8] ----
    #pragma unroll
    for (int k = 0; k < 8; ++k) {
        const int idx = k * 256 + tid;
        const int c = idx >> 3, o = idx & 7;
        s_w[idx] = (o < O_N) ? w[o * C_N + c] : 0.0f;
    }

    // ---- prologue B: antialias triangle resize (jax.image.resize), fixed
    //      7x5 window, 35 independent loads ----
    {
        const int pg = blockIdx.x * 256 + tid;      // global pixel, < 69120 exact
        const int a  = pg / P_N;
        const int p  = pg - a * P_N;
        const int oy = p / W_N, ox = p - oy * W_N;
        const float ksy = 256.0f / 80.0f;
        const float ksx = 256.0f / 108.0f;
        const float rky = 0.3125f;          // 80/256 exact
        const float rkx = 0.421875f;        // 108/256 exact
        const float sfy = ((float)oy + 0.5f) * ksy - 0.5f;
        const float sfx = ((float)ox + 0.5f) * ksx - 0.5f;
        const int iyS = (int)ceilf(sfy - ksy);
        const int ixS = (int)ceilf(sfx - ksx);

        float wxv[5];
        float wxs = 0.0f;
        #pragma unroll
        for (int q = 0; q < 5; ++q) {
            const int ix = ixS + q;
            float wv = fmaxf(0.0f, 1.0f - fabsf(sfx - (float)ix) * rkx);
            wv = (ix >= 0 && ix < MW) ? wv : 0.0f;
            wxv[q] = wv;
            wxs += wv;
        }
        const float* mp = masks + (size_t)a * (MH * MW);
        float acm = 0.0f, wys = 0.0f;
        #pragma unroll
        for (int r = 0; r < 7; ++r) {
            const int iy = iyS + r;
            float wy = fmaxf(0.0f, 1.0f - fabsf(sfy - (float)iy) * rky);
            wy = (iy >= 0 && iy < MH) ? wy : 0.0f;
            wys += wy;
            const float* row = mp + min(max(iy, 0), MH - 1) * MW;
            float rs = 0.0f;
            #pragma unroll
            for (int q = 0; q < 5; ++q)
                rs = fmaf(wxv[q], row[min(max(ixS + q, 0), MW - 1)], rs);
            acm = fmaf(wy, rs, acm);
        }
        s_cm[tid] = acm / (wys * wxs);
    }
    __syncthreads();   // w+cm visible; prologue vmem drained -> vmcnt=0 here

    // ---- per-lane global column ----
    const int g4     = blockIdx.x * 64 + lane;      // < 17280 exact, no tail
    const int a      = g4 / P4_N;
    const int px4in  = g4 - a * P4_N;
    const float* xa  = x + (size_t)a * C_N * P_N + (size_t)px4in * 4;

    const float4 cm4 = make_float4(s_cm[lane * 4], s_cm[lane * 4 + 1],
                                   s_cm[lane * 4 + 2], s_cm[lane * 4 + 3]);

    float4 acc[O_N];
    #pragma unroll
    for (int o = 0; o < O_N; ++o) acc[o] = make_float4(0.f, 0.f, 0.f, 0.f);

    // wave-private staging region: s_x + wid*4096 floats
#define STAGE(i)                                                               \
    { _Pragma("unroll")                                                        \
      for (int j = 0; j < 4; ++j) {                                            \
          const int c = wid * 64 + (i) * 4 + j;                                \
          const float* gs = xa + (size_t)c * P_N;                              \
          __builtin_amdgcn_global_load_lds(                                    \
              (const __attribute__((address_space(1))) void*)gs,               \
              (__attribute__((address_space(3))) void*)(s_x + wid * 4096 +     \
                                      ((i) & 3) * 1024 + j * 256),             \
              16, 0, 0);                                                       \
      } }

#define COMP(i)                                                                \
    { _Pragma("unroll")                                                        \
      for (int j = 0; j < 4; ++j) {                                            \
          const int c = wid * 64 + (i) * 4 + j;                                \
          float4 v = *reinterpret_cast<const float4*>(                         \
                         s_x + wid * 4096 + ((i) & 3) * 1024 + j * 256 + lane * 4); \
          v.x += cm4.x; v.y += cm4.y; v.z += cm4.z; v.w += cm4.w;              \
          const float4 wA = *reinterpret_cast<const float4*>(s_w + c * 8);     \
          const float4 wB = *reinterpret_cast<const float4*>(s_w + c * 8 + 4); \
          acc[0].x = fmaf(wA.x, v.x, acc[0].x); acc[0].y = fmaf(wA.x, v.y, acc[0].y); \
          acc[0].z = fmaf(wA.x, v.z, acc[0].z); acc[0].w = fmaf(wA.x, v.w, acc[0].w); \
          acc[1].x = fmaf(wA.y, v.x, acc[1].x); acc[1].y = fmaf(wA.y, v.y, acc[1].y); \
          acc[1].z = fmaf(wA.y, v.z, acc[1].z); acc[1].w = fmaf(wA.y, v.w, acc[1].w); \
          acc[2].x = fmaf(wA.z, v.x, acc[2].x); acc[2].y = fmaf(wA.z, v.y, acc[2].y); \
          acc[2].z = fmaf(wA.z, v.z, acc[2].z); acc[2].w = fmaf(wA.z, v.w, acc[2].w); \
          acc[3].x = fmaf(wA.w, v.x, acc[3].x); acc[3].y = fmaf(wA.w, v.y, acc[3].y); \
          acc[3].z = fmaf(wA.w, v.z, acc[3].z); acc[3].w = fmaf(wA.w, v.w, acc[3].w); \
          acc[4].x = fmaf(wB.x, v.x, acc[4].x); acc[4].y = fmaf(wB.x, v.y, acc[4].y); \
          acc[4].z = fmaf(wB.x, v.z, acc[4].z); acc[4].w = fmaf(wB.x, v.w, acc[4].w); \
          acc[5].x = fmaf(wB.y, v.x, acc[5].x); acc[5].y = fmaf(wB.y, v.y, acc[5].y); \
          acc[5].z = fmaf(wB.y, v.z, acc[5].z); acc[5].w = fmaf(wB.y, v.w, acc[5].w); \
          acc[6].x = fmaf(wB.z, v.x, acc[6].x); acc[6].y = fmaf(wB.z, v.y, acc[6].y); \
          acc[6].z = fmaf(wB.z, v.z, acc[6].z); acc[6].w = fmaf(wB.z, v.w, acc[6].w); \
      } }

    STAGE(0) STAGE(1) STAGE(2)
    #pragma unroll
    for (int i = 0; i < 16; ++i) {
        if (i < 13) {
            STAGE(i + 3)
            asm volatile("s_waitcnt vmcnt(12)" ::: "memory");
        } else if (i == 13) {
            asm volatile("s_waitcnt vmcnt(8)" ::: "memory");
        } else if (i == 14) {
            asm volatile("s_waitcnt vmcnt(4)" ::: "memory");
        } else {
            asm volatile("s_waitcnt vmcnt(0)" ::: "memory");
        }
        COMP(i)
    }
#undef STAGE
#undef COMP

    // ---- cross-wave reduce: reuse s_x (32KB needed <= 64KB) ----
    __syncthreads();
    float4* sred = reinterpret_cast<float4*>(s_x);
    #pragma unroll
    for (int o = 0; o < O_N; ++o)
        sred[(wid * 64 + lane) * 8 + o] = acc[o];
    __syncthreads();

    // 448 (px-slot, o) pairs over 256 threads (STRIDED; r9 lesson)
    for (int pair = tid; pair < 64 * O_N; pair += 256) {
        const int pl = pair & 63;
        const int o  = pair >> 6;
        const int g4p    = blockIdx.x * 64 + pl;
        const int a2     = g4p / P4_N;
        const int px4in2 = g4p - a2 * P4_N;
        const float4 s0 = sred[(0 * 64 + pl) * 8 + o];
        const float4 s1 = sred[(1 * 64 + pl) * 8 + o];
        const float4 s2 = sred[(2 * 64 + pl) * 8 + o];
        const float4 s3 = sred[(3 * 64 + pl) * 8 + o];
        float4 zv;
        zv.x = s0.x + s1.x + s2.x + s3.x;
        zv.y = s0.y + s1.y + s2.y + s3.y;
        zv.z = s0.z + s1.z + s2.z + s3.z;
        zv.w = s0.w + s1.w + s2.w + s3.w;
        const float bo = b[o];
        const size_t ob = (size_t)(a2 * O_N + o) * P4_N + px4in2;
        reinterpret_cast<float4*>(z)[ob] = zv;
        float4 sv;
        sv.x = sigmoidf_(zv.x + bo);
        sv.y = sigmoidf_(zv.y + bo);
        sv.z = sigmoidf_(zv.z + bo);
        sv.w = sigmoidf_(zv.w + bo);
        reinterpret_cast<float4*>(ssolo)[ob] = sv;
    }
}

// ---------------------------------------------------------------------------
// Aggregation: per ego i, pixel p: saggr = sigmoid(b + sum_j adj[i,j]!=0 ?
//              zero-padded-bilinear(z[j], rel[i,j] @ [u,v,1]) : 0)
// z planes total 1.9 MB — L2-resident gathers. 1080 blocks x 64.
// ---------------------------------------------------------------------------
__launch_bounds__(64)
__global__ void k_aggr(const float* __restrict__ z, const float* __restrict__ rel,
                       const int* __restrict__ adj, const float* __restrict__ b,
                       float* __restrict__ saggr)
{
    const int i = blockIdx.x / 135;
    const int p = (blockIdx.x - i * 135) * 64 + threadIdx.x;
    const int vy = p / W_N, ux = p - vy * W_N;
    const float fu = (float)ux, fv = (float)vy;

    float acc[O_N];
    #pragma unroll
    for (int o = 0; o < O_N; ++o) acc[o] = b[o];

    for (int j = 0; j < A_N; ++j) {
        if (adj[i * A_N + j] == 0) continue;
        const float* M = rel + (i * A_N + j) * 6;
        float sx = M[0] * fu + M[1] * fv + M[2];
        float sy = M[3] * fu + M[4] * fv + M[5];
        if (!(sx > -1.0f && sx < (float)W_N && sy > -1.0f && sy < (float)H_N)) continue;
        float x0f = floorf(sx), y0f = floorf(sy);
        float wx = sx - x0f, wy = sy - y0f;
        int x0 = (int)x0f, y0 = (int)y0f;
        int x1 = x0 + 1,  y1 = y0 + 1;
        float w00 = (1.0f - wy) * (1.0f - wx), w01 = (1.0f - wy) * wx;
        float w10 = wy * (1.0f - wx),          w11 = wy * wx;
        if (x0 < 0)    { w00 = 0.0f; w10 = 0.0f; x0 = 0; }
        if (x1 >= W_N) { w01 = 0.0f; w11 = 0.0f; x1 = W_N - 1; }
        if (y0 < 0)    { w00 = 0.0f; w01 = 0.0f; y0 = 0; }
        if (y1 >= H_N) { w10 = 0.0f; w11 = 0.0f; y1 = H_N - 1; }
        const int i00 = y0 * W_N + x0, i01 = y0 * W_N + x1;
        const int i10 = y1 * W_N + x0, i11 = y1 * W_N + x1;
        const float* zj = z + j * O_N * P_N;
        #pragma unroll
        for (int o = 0; o < O_N; ++o) {
            const float* zp = zj + o * P_N;
            acc[o] += w00 * zp[i00] + w01 * zp[i01] + w10 * zp[i10] + w11 * zp[i11];
        }
    }
    const int ob = i * O_N * P_N + p;
    #pragma unroll
    for (int o = 0; o < O_N; ++o) saggr[ob + o * P_N] = sigmoidf_(acc[o]);
}

// ---------------------------------------------------------------------------
// Upsample: align_corners=True bilinear 80x108 -> 256x256, f32 out.
// 4 px/thread -> float4 stores; 7168 blocks x 256 exact.
// Output layout: [solo(8,7,256,256), aggr(8,7,256,256)] flat f32.
// ---------------------------------------------------------------------------
__launch_bounds__(256)
__global__ void k_upsample(const float* __restrict__ ssolo, const float* __restrict__ saggr,
                           float* __restrict__ out)
{
    const int idx = blockIdx.x * 256 + threadIdx.x;   // quad index
    int k = idx;
    const int oxq = k & 63;   k >>= 6;
    const int oy  = k & 255;  k >>= 8;
    const int o   = k % O_N;  k /= O_N;
    const int a   = k & 7;    k >>= 3;
    const int t   = k;        // 0 = solo, 1 = aggr

    const float* src = (t == 0 ? ssolo : saggr) + (a * O_N + o) * P_N;
    float syf = (float)oy * (79.0f / 255.0f);
    int y0 = (int)syf; y0 = min(y0, H_N - 2);
    float wy = syf - (float)y0;
    const float* r0 = src + y0 * W_N;
    const float* r1 = r0 + W_N;

    float res[4];
    #pragma unroll
    for (int q = 0; q < 4; ++q) {
        int ox = oxq * 4 + q;
        float sxf = (float)ox * (107.0f / 255.0f);
        int x0 = (int)sxf; x0 = min(x0, W_N - 2);
        float wx = sxf - (float)x0;
        float c0 = r0[x0]     * (1.0f - wy) + r1[x0]     * wy;
        float c1 = r0[x0 + 1] * (1.0f - wy) + r1[x0 + 1] * wy;
        res[q] = c0 * (1.0f - wx) + c1 * wx;
    }
    *reinterpret_cast<float4*>(out + (size_t)idx * 4) =
        make_float4(res[0], res[1], res[2], res[3]);
}

// ---------------------------------------------------------------------------
extern "C" void kernel_launch(void* const* d_in, const int* in_sizes, int n_in,
                              void* d_out, int out_size, void* d_ws, size_t ws_size,
                              hipStream_t stream)
{
    (void)in_sizes; (void)n_in; (void)out_size; (void)ws_size;
    const float* x    = (const float*)d_in[0];
    const float* rel  = (const float*)d_in[1];
    const int*   adj  = (const int*)d_in[2];
    const float* cmsk = (const float*)d_in[3];
    const float* wcls = (const float*)d_in[4];
    const float* bcls = (const float*)d_in[5];
    float* out = (float*)d_out;   // reference output dtype is float32

    float* ws    = (float*)d_ws;
    float* z     = ws;                          // 8*7*8640 = 483,840 f32
    float* ssolo = z     + A_N * O_N * P_N;
    float* saggr = ssolo + A_N * O_N * P_N;     // total ~5.8 MB

    k_conv    <<<270, 256, 0, stream>>>(x, cmsk, wcls, bcls, z, ssolo);
    k_aggr    <<<1080, 64, 0, stream>>>(z, rel, adj, bcls, saggr);
    k_upsample<<<7168, 256, 0, stream>>>(ssolo, saggr, out);
}

// Round 13
// 49.248 us; speedup vs baseline: 2.2725x; 2.2725x over previous
//
#include <hip/hip_runtime.h>
#include <hip/hip_bf16.h>

#define A_N 8
#define C_N 256
#define H_N 80
#define W_N 108
#define P_N (H_N * W_N)      // 8640
#define P4_N (P_N / 4)       // 2160 float4 columns per plane
#define O_N 7
#define MH 256
#define MW 256
#define OUT_HW 256

__device__ __forceinline__ float sigmoidf_(float zv) {
    return 1.0f / (1.0f + __expf(-zv));
}

// ---------------------------------------------------------------------------
// Fused resize + conv. Grid 270 x 256 thr (4 waves), zero tail.
// Wave-PRIVATE pipelined staging: each wave owns 16KB LDS (4 slots x 4ch x
// 1KB), stages its 64-channel quarter via global_load_lds in 16 batches of 4,
// counted s_waitcnt vmcnt(12) -> 3 batches (12KB/wave, 48KB/CU) in flight.
// No barriers in the loop. r12 fix: __launch_bounds__(256,1) -- without it
// the VGPR cap of 64 spilled acc[] to scratch each step (107MB of writes,
// vmcnt polluted by scratch ops). r12 fix 2: conflict-free sred layout.
// ---------------------------------------------------------------------------
__launch_bounds__(256, 1)
__global__ void k_conv(const float* __restrict__ x, const float* __restrict__ masks,
                       const float* __restrict__ w, const float* __restrict__ b,
                       float* __restrict__ z, float* __restrict__ ssolo)
{
    __shared__ float s_x[16384];   // 4 waves x 4 slots x 4 ch x 256 floats (64KB)
    __shared__ float s_w[2048];    // w transposed [c][8]
    __shared__ float s_cm[256];    // resized mask for this block's 256 px

    const int tid  = threadIdx.x;
    const int lane = tid & 63;
    const int wid  = tid >> 6;

    // ---- prologue A: stage w -> LDS as [c][8] ----
    #pragma unroll
    for (int k = 0; k < 8; ++k) {
        const int idx = k * 256 + tid;
        const int c = idx >> 3, o = idx & 7;
        s_w[idx] = (o < O_N) ? w[o * C_N + c] : 0.0f;
    }

    // ---- prologue B: antialias triangle resize (jax.image.resize), fixed
    //      7x5 window, 35 independent loads ----
    {
        const int pg = blockIdx.x * 256 + tid;      // global pixel, < 69120 exact
        const int a  = pg / P_N;
        const int p  = pg - a * P_N;
        const int oy = p / W_N, ox = p - oy * W_N;
        const float ksy = 256.0f / 80.0f;
        const float ksx = 256.0f / 108.0f;
        const float rky = 0.3125f;          // 80/256 exact
        const float rkx = 0.421875f;        // 108/256 exact
        const float sfy = ((float)oy + 0.5f) * ksy - 0.5f;
        const float sfx = ((float)ox + 0.5f) * ksx - 0.5f;
        const int iyS = (int)ceilf(sfy - ksy);
        const int ixS = (int)ceilf(sfx - ksx);

        float wxv[5];
        float wxs = 0.0f;
        #pragma unroll
        for (int q = 0; q < 5; ++q) {
            const int ix = ixS + q;
            float wv = fmaxf(0.0f, 1.0f - fabsf(sfx - (float)ix) * rkx);
            wv = (ix >= 0 && ix < MW) ? wv : 0.0f;
            wxv[q] = wv;
            wxs += wv;
        }
        const float* mp = masks + (size_t)a * (MH * MW);
        float acm = 0.0f, wys = 0.0f;
        #pragma unroll
        for (int r = 0; r < 7; ++r) {
            const int iy = iyS + r;
            float wy = fmaxf(0.0f, 1.0f - fabsf(sfy - (float)iy) * rky);
            wy = (iy >= 0 && iy < MH) ? wy : 0.0f;
            wys += wy;
            const float* row = mp + min(max(iy, 0), MH - 1) * MW;
            float rs = 0.0f;
            #pragma unroll
            for (int q = 0; q < 5; ++q)
                rs = fmaf(wxv[q], row[min(max(ixS + q, 0), MW - 1)], rs);
            acm = fmaf(wy, rs, acm);
        }
        s_cm[tid] = acm / (wys * wxs);
    }
    __syncthreads();   // w+cm visible; prologue vmem drained -> vmcnt=0 here

    // ---- per-lane global column ----
    const int g4     = blockIdx.x * 64 + lane;      // < 17280 exact, no tail
    const int a      = g4 / P4_N;
    const int px4in  = g4 - a * P4_N;
    const float* xa  = x + (size_t)a * C_N * P_N + (size_t)px4in * 4;

    const float4 cm4 = make_float4(s_cm[lane * 4], s_cm[lane * 4 + 1],
                                   s_cm[lane * 4 + 2], s_cm[lane * 4 + 3]);

    float4 acc[O_N];
    #pragma unroll
    for (int o = 0; o < O_N; ++o) acc[o] = make_float4(0.f, 0.f, 0.f, 0.f);

    // wave-private staging region: s_x + wid*4096 floats
#define STAGE(i)                                                               \
    { _Pragma("unroll")                                                        \
      for (int j = 0; j < 4; ++j) {                                            \
          const int c = wid * 64 + (i) * 4 + j;                                \
          const float* gs = xa + (size_t)c * P_N;                              \
          __builtin_amdgcn_global_load_lds(                                    \
              (const __attribute__((address_space(1))) void*)gs,               \
              (__attribute__((address_space(3))) void*)(s_x + wid * 4096 +     \
                                      ((i) & 3) * 1024 + j * 256),             \
              16, 0, 0);                                                       \
      } }

#define COMP(i)                                                                \
    { _Pragma("unroll")                                                        \
      for (int j = 0; j < 4; ++j) {                                            \
          const int c = wid * 64 + (i) * 4 + j;                                \
          float4 v = *reinterpret_cast<const float4*>(                         \
                         s_x + wid * 4096 + ((i) & 3) * 1024 + j * 256 + lane * 4); \
          v.x += cm4.x; v.y += cm4.y; v.z += cm4.z; v.w += cm4.w;              \
          const float4 wA = *reinterpret_cast<const float4*>(s_w + c * 8);     \
          const float4 wB = *reinterpret_cast<const float4*>(s_w + c * 8 + 4); \
          acc[0].x = fmaf(wA.x, v.x, acc[0].x); acc[0].y = fmaf(wA.x, v.y, acc[0].y); \
          acc[0].z = fmaf(wA.x, v.z, acc[0].z); acc[0].w = fmaf(wA.x, v.w, acc[0].w); \
          acc[1].x = fmaf(wA.y, v.x, acc[1].x); acc[1].y = fmaf(wA.y, v.y, acc[1].y); \
          acc[1].z = fmaf(wA.y, v.z, acc[1].z); acc[1].w = fmaf(wA.y, v.w, acc[1].w); \
          acc[2].x = fmaf(wA.z, v.x, acc[2].x); acc[2].y = fmaf(wA.z, v.y, acc[2].y); \
          acc[2].z = fmaf(wA.z, v.z, acc[2].z); acc[2].w = fmaf(wA.z, v.w, acc[2].w); \
          acc[3].x = fmaf(wA.w, v.x, acc[3].x); acc[3].y = fmaf(wA.w, v.y, acc[3].y); \
          acc[3].z = fmaf(wA.w, v.z, acc[3].z); acc[3].w = fmaf(wA.w, v.w, acc[3].w); \
          acc[4].x = fmaf(wB.x, v.x, acc[4].x); acc[4].y = fmaf(wB.x, v.y, acc[4].y); \
          acc[4].z = fmaf(wB.x, v.z, acc[4].z); acc[4].w = fmaf(wB.x, v.w, acc[4].w); \
          acc[5].x = fmaf(wB.y, v.x, acc[5].x); acc[5].y = fmaf(wB.y, v.y, acc[5].y); \
          acc[5].z = fmaf(wB.y, v.z, acc[5].z); acc[5].w = fmaf(wB.y, v.w, acc[5].w); \
          acc[6].x = fmaf(wB.z, v.x, acc[6].x); acc[6].y = fmaf(wB.z, v.y, acc[6].y); \
          acc[6].z = fmaf(wB.z, v.z, acc[6].z); acc[6].w = fmaf(wB.z, v.w, acc[6].w); \
      } }

    STAGE(0) STAGE(1) STAGE(2)
    #pragma unroll
    for (int i = 0; i < 16; ++i) {
        if (i < 13) {
            STAGE(i + 3)
            asm volatile("s_waitcnt vmcnt(12)" ::: "memory");
        } else if (i == 13) {
            asm volatile("s_waitcnt vmcnt(8)" ::: "memory");
        } else if (i == 14) {
            asm volatile("s_waitcnt vmcnt(4)" ::: "memory");
        } else {
            asm volatile("s_waitcnt vmcnt(0)" ::: "memory");
        }
        COMP(i)
    }
#undef STAGE
#undef COMP

    // ---- cross-wave reduce: reuse s_x (28KB <= 64KB), conflict-free layout
    //      sred[(o*4+wid)*64+lane]: 16B/lane contiguous on write AND read ----
    __syncthreads();
    float4* sred = reinterpret_cast<float4*>(s_x);
    #pragma unroll
    for (int o = 0; o < O_N; ++o)
        sred[(o * 4 + wid) * 64 + lane] = acc[o];
    __syncthreads();

    // 448 (px-slot, o) pairs over 256 threads (STRIDED; r9 lesson)
    for (int pair = tid; pair < 64 * O_N; pair += 256) {
        const int pl = pair & 63;
        const int o  = pair >> 6;
        const int g4p    = blockIdx.x * 64 + pl;
        const int a2     = g4p / P4_N;
        const int px4in2 = g4p - a2 * P4_N;
        const float4 s0 = sred[(o * 4 + 0) * 64 + pl];
        const float4 s1 = sred[(o * 4 + 1) * 64 + pl];
        const float4 s2 = sred[(o * 4 + 2) * 64 + pl];
        const float4 s3 = sred[(o * 4 + 3) * 64 + pl];
        float4 zv;
        zv.x = s0.x + s1.x + s2.x + s3.x;
        zv.y = s0.y + s1.y + s2.y + s3.y;
        zv.z = s0.z + s1.z + s2.z + s3.z;
        zv.w = s0.w + s1.w + s2.w + s3.w;
        const float bo = b[o];
        const size_t ob = (size_t)(a2 * O_N + o) * P4_N + px4in2;
        reinterpret_cast<float4*>(z)[ob] = zv;
        float4 sv;
        sv.x = sigmoidf_(zv.x + bo);
        sv.y = sigmoidf_(zv.y + bo);
        sv.z = sigmoidf_(zv.z + bo);
        sv.w = sigmoidf_(zv.w + bo);
        reinterpret_cast<float4*>(ssolo)[ob] = sv;
    }
}

// ---------------------------------------------------------------------------
// Aggregation: per ego i, pixel p: saggr = sigmoid(b + sum_j adj[i,j]!=0 ?
//              zero-padded-bilinear(z[j], rel[i,j] @ [u,v,1]) : 0)
// z planes total 1.9 MB — L2-resident gathers. 1080 blocks x 64.
// ---------------------------------------------------------------------------
__launch_bounds__(64)
__global__ void k_aggr(const float* __restrict__ z, const float* __restrict__ rel,
                       const int* __restrict__ adj, const float* __restrict__ b,
                       float* __restrict__ saggr)
{
    const int i = blockIdx.x / 135;
    const int p = (blockIdx.x - i * 135) * 64 + threadIdx.x;
    const int vy = p / W_N, ux = p - vy * W_N;
    const float fu = (float)ux, fv = (float)vy;

    float acc[O_N];
    #pragma unroll
    for (int o = 0; o < O_N; ++o) acc[o] = b[o];

    for (int j = 0; j < A_N; ++j) {
        if (adj[i * A_N + j] == 0) continue;
        const float* M = rel + (i * A_N + j) * 6;
        float sx = M[0] * fu + M[1] * fv + M[2];
        float sy = M[3] * fu + M[4] * fv + M[5];
        if (!(sx > -1.0f && sx < (float)W_N && sy > -1.0f && sy < (float)H_N)) continue;
        float x0f = floorf(sx), y0f = floorf(sy);
        float wx = sx - x0f, wy = sy - y0f;
        int x0 = (int)x0f, y0 = (int)y0f;
        int x1 = x0 + 1,  y1 = y0 + 1;
        float w00 = (1.0f - wy) * (1.0f - wx), w01 = (1.0f - wy) * wx;
        float w10 = wy * (1.0f - wx),          w11 = wy * wx;
        if (x0 < 0)    { w00 = 0.0f; w10 = 0.0f; x0 = 0; }
        if (x1 >= W_N) { w01 = 0.0f; w11 = 0.0f; x1 = W_N - 1; }
        if (y0 < 0)    { w00 = 0.0f; w01 = 0.0f; y0 = 0; }
        if (y1 >= H_N) { w10 = 0.0f; w11 = 0.0f; y1 = H_N - 1; }
        const int i00 = y0 * W_N + x0, i01 = y0 * W_N + x1;
        const int i10 = y1 * W_N + x0, i11 = y1 * W_N + x1;
        const float* zj = z + j * O_N * P_N;
        #pragma unroll
        for (int o = 0; o < O_N; ++o) {
            const float* zp = zj + o * P_N;
            acc[o] += w00 * zp[i00] + w01 * zp[i01] + w10 * zp[i10] + w11 * zp[i11];
        }
    }
    const int ob = i * O_N * P_N + p;
    #pragma unroll
    for (int o = 0; o < O_N; ++o) saggr[ob + o * P_N] = sigmoidf_(acc[o]);
}

// ---------------------------------------------------------------------------
// Upsample: align_corners=True bilinear 80x108 -> 256x256, f32 out.
// 4 px/thread -> float4 stores; 7168 blocks x 256 exact.
// Output layout: [solo(8,7,256,256), aggr(8,7,256,256)] flat f32.
// ---------------------------------------------------------------------------
__launch_bounds__(256)
__global__ void k_upsample(const float* __restrict__ ssolo, const float* __restrict__ saggr,
                           float* __restrict__ out)
{
    const int idx = blockIdx.x * 256 + threadIdx.x;   // quad index
    int k = idx;
    const int oxq = k & 63;   k >>= 6;
    const int oy  = k & 255;  k >>= 8;
    const int o   = k % O_N;  k /= O_N;
    const int a   = k & 7;    k >>= 3;
    const int t   = k;        // 0 = solo, 1 = aggr

    const float* src = (t == 0 ? ssolo : saggr) + (a * O_N + o) * P_N;
    float syf = (float)oy * (79.0f / 255.0f);
    int y0 = (int)syf; y0 = min(y0, H_N - 2);
    float wy = syf - (float)y0;
    const float* r0 = src + y0 * W_N;
    const float* r1 = r0 + W_N;

    float res[4];
    #pragma unroll
    for (int q = 0; q < 4; ++q) {
        int ox = oxq * 4 + q;
        float sxf = (float)ox * (107.0f / 255.0f);
        int x0 = (int)sxf; x0 = min(x0, W_N - 2);
        float wx = sxf - (float)x0;
        float c0 = r0[x0]     * (1.0f - wy) + r1[x0]     * wy;
        float c1 = r0[x0 + 1] * (1.0f - wy) + r1[x0 + 1] * wy;
        res[q] = c0 * (1.0f - wx) + c1 * wx;
    }
    *reinterpret_cast<float4*>(out + (size_t)idx * 4) =
        make_float4(res[0], res[1], res[2], res[3]);
}

// ---------------------------------------------------------------------------
extern "C" void kernel_launch(void* const* d_in, const int* in_sizes, int n_in,
                              void* d_out, int out_size, void* d_ws, size_t ws_size,
                              hipStream_t stream)
{
    (void)in_sizes; (void)n_in; (void)out_size; (void)ws_size;
    const float* x    = (const float*)d_in[0];
    const float* rel  = (const float*)d_in[1];
    const int*   adj  = (const int*)d_in[2];
    const float* cmsk = (const float*)d_in[3];
    const float* wcls = (const float*)d_in[4];
    const float* bcls = (const float*)d_in[5];
    float* out = (float*)d_out;   // reference output dtype is float32

    float* ws    = (float*)d_ws;
    float* z     = ws;                          // 8*7*8640 = 483,840 f32
    float* ssolo = z     + A_N * O_N * P_N;
    float* saggr = ssolo + A_N * O_N * P_N;     // total ~5.8 MB

    k_conv    <<<270, 256, 0, stream>>>(x, cmsk, wcls, bcls, z, ssolo);
    k_aggr    <<<1080, 64, 0, stream>>>(z, rel, adj, bcls, saggr);
    k_upsample<<<7168, 256, 0, stream>>>(ssolo, saggr, out);
}

// Round 14
// 41.878 us; speedup vs baseline: 2.6725x; 1.1760x over previous
//
#include <hip/hip_runtime.h>
#include <hip/hip_bf16.h>

#define A_N 8
#define C_N 256
#define H_N 80
#define W_N 108
#define P_N (H_N * W_N)      // 8640
#define P4_N (P_N / 4)       // 2160 float4 columns per plane
#define O_N 7
#define MH 256
#define MW 256
#define OUT_HW 256
#define BPA 135              // 16-px4 tiles per agent (135*16 = 2160 exact)

__device__ __forceinline__ float sigmoidf_(float zv) {
    return 1.0f / (1.0f + __expf(-zv));
}

// ---------------------------------------------------------------------------
// Fused resize + conv, MAX-OCCUPANCY shape (r13 post-mortem law: BW ~
// waves/CU x bytes-in-flight/wave; hipcc gives ~1-2 loads in flight/wave,
// so the lever is wave count). Grid 8*135 = 1080 blocks x 256 thr
// (~4.2 blocks/CU = 17 waves/CU; LDS 15.3KB, VGPR <= 128 -> no spill).
// Block = 16 px4 (64 px) x 256 ch. Wave wid: channels wid*64..+63;
// lane = cs*16+p: p = px4-in-tile, cs = 16-ch subgroup. Per-lane 16 channels,
// 2-deep load buffer. cm folded into FMA input: acc += w*(x+cm).
// Reduce: shfl_xor over cs (16,32) then 7KB-LDS cross-wave.
// ---------------------------------------------------------------------------
__launch_bounds__(256, 2)
__global__ void k_conv(const float* __restrict__ x, const float* __restrict__ masks,
                       const float* __restrict__ w, const float* __restrict__ b,
                       float* __restrict__ z, float* __restrict__ ssolo)
{
    __shared__ float  s_w[2048];             // w transposed [c][8]  (8 KB)
    __shared__ float4 s_red[4][16][O_N];     // per-wave partials    (7 KB)
    __shared__ float  s_cm[64];              // resized mask, 64 px  (256 B)

    const int tid  = threadIdx.x;
    const int lane = tid & 63;
    const int wid  = tid >> 6;
    const int a    = blockIdx.x / BPA;
    const int tile = blockIdx.x - a * BPA;

    // ---- stage w -> LDS as [c][8] (all 2048 entries; r9 lesson) ----
    #pragma unroll
    for (int k = 0; k < 8; ++k) {
        const int idx = k * 256 + tid;
        const int c = idx >> 3, o = idx & 7;
        s_w[idx] = (o < O_N) ? w[o * C_N + c] : 0.0f;
    }

    // ---- inline antialias resize (jax.image.resize bilinear, antialias),
    //      fixed 7x5 window, threads 0..63 (one per px of this tile) ----
    if (tid < 64) {
        const int p  = tile * 64 + tid;          // within-agent pixel, < 8640
        const int oy = p / W_N, ox = p - oy * W_N;
        const float ksy = 256.0f / 80.0f;
        const float ksx = 256.0f / 108.0f;
        const float rky = 0.3125f;               // 80/256 exact
        const float rkx = 0.421875f;             // 108/256 exact
        const float sfy = ((float)oy + 0.5f) * ksy - 0.5f;
        const float sfx = ((float)ox + 0.5f) * ksx - 0.5f;
        const int iyS = (int)ceilf(sfy - ksy);
        const int ixS = (int)ceilf(sfx - ksx);

        float wxv[5];
        float wxs = 0.0f;
        #pragma unroll
        for (int q = 0; q < 5; ++q) {
            const int ix = ixS + q;
            float wv = fmaxf(0.0f, 1.0f - fabsf(sfx - (float)ix) * rkx);
            wv = (ix >= 0 && ix < MW) ? wv : 0.0f;
            wxv[q] = wv;
            wxs += wv;
        }
        const float* mp = masks + (size_t)a * (MH * MW);
        float acm = 0.0f, wys = 0.0f;
        #pragma unroll
        for (int r = 0; r < 7; ++r) {
            const int iy = iyS + r;
            float wy = fmaxf(0.0f, 1.0f - fabsf(sfy - (float)iy) * rky);
            wy = (iy >= 0 && iy < MH) ? wy : 0.0f;
            wys += wy;
            const float* row = mp + min(max(iy, 0), MH - 1) * MW;
            float rs = 0.0f;
            #pragma unroll
            for (int q = 0; q < 5; ++q)
                rs = fmaf(wxv[q], row[min(max(ixS + q, 0), MW - 1)], rs);
            acm = fmaf(wy, rs, acm);
        }
        s_cm[tid] = acm / (wys * wxs);
    }
    __syncthreads();

    // ---- streaming conv: 16 channels per lane, 2-deep buffer ----
    const int p   = lane & 15;               // px4 within tile
    const int cs  = lane >> 4;               // channel subgroup
    const int px4 = tile * 16 + p;           // < 2160 exact, no clamp
    const int cb  = wid * 64 + cs * 16;      // lane's first channel

    const float* xp = x + ((size_t)a * C_N + cb) * P_N + (size_t)px4 * 4;

    const float4 cm4 = make_float4(s_cm[p * 4], s_cm[p * 4 + 1],
                                   s_cm[p * 4 + 2], s_cm[p * 4 + 3]);

    float4 acc[O_N];
    #pragma unroll
    for (int o = 0; o < O_N; ++o) acc[o] = make_float4(0.f, 0.f, 0.f, 0.f);

    float4 vb0, vb1;
    vb0 = *reinterpret_cast<const float4*>(xp);
    #pragma unroll
    for (int k = 0; k < 16; ++k) {
        if (k < 15) {
            const float4 vn = *reinterpret_cast<const float4*>(xp + (size_t)(k + 1) * P_N);
            if ((k & 1) == 0) vb1 = vn; else vb0 = vn;
        }
        float4 v = ((k & 1) == 0) ? vb0 : vb1;
        v.x += cm4.x; v.y += cm4.y; v.z += cm4.z; v.w += cm4.w;
        const float4 wA = *reinterpret_cast<const float4*>(s_w + (cb + k) * 8);
        const float4 wB = *reinterpret_cast<const float4*>(s_w + (cb + k) * 8 + 4);
        acc[0].x = fmaf(wA.x, v.x, acc[0].x); acc[0].y = fmaf(wA.x, v.y, acc[0].y);
        acc[0].z = fmaf(wA.x, v.z, acc[0].z); acc[0].w = fmaf(wA.x, v.w, acc[0].w);
        acc[1].x = fmaf(wA.y, v.x, acc[1].x); acc[1].y = fmaf(wA.y, v.y, acc[1].y);
        acc[1].z = fmaf(wA.y, v.z, acc[1].z); acc[1].w = fmaf(wA.y, v.w, acc[1].w);
        acc[2].x = fmaf(wA.z, v.x, acc[2].x); acc[2].y = fmaf(wA.z, v.y, acc[2].y);
        acc[2].z = fmaf(wA.z, v.z, acc[2].z); acc[2].w = fmaf(wA.z, v.w, acc[2].w);
        acc[3].x = fmaf(wA.w, v.x, acc[3].x); acc[3].y = fmaf(wA.w, v.y, acc[3].y);
        acc[3].z = fmaf(wA.w, v.z, acc[3].z); acc[3].w = fmaf(wA.w, v.w, acc[3].w);
        acc[4].x = fmaf(wB.x, v.x, acc[4].x); acc[4].y = fmaf(wB.x, v.y, acc[4].y);
        acc[4].z = fmaf(wB.x, v.z, acc[4].z); acc[4].w = fmaf(wB.x, v.w, acc[4].w);
        acc[5].x = fmaf(wB.y, v.x, acc[5].x); acc[5].y = fmaf(wB.y, v.y, acc[5].y);
        acc[5].z = fmaf(wB.y, v.z, acc[5].z); acc[5].w = fmaf(wB.y, v.w, acc[5].w);
        acc[6].x = fmaf(wB.z, v.x, acc[6].x); acc[6].y = fmaf(wB.z, v.y, acc[6].y);
        acc[6].z = fmaf(wB.z, v.z, acc[6].z); acc[6].w = fmaf(wB.z, v.w, acc[6].w);
    }

    // ---- intra-wave reduce over cs: xor-butterfly lanes 16, 32 ----
    #pragma unroll
    for (int o = 0; o < O_N; ++o) {
        acc[o].x += __shfl_xor(acc[o].x, 16); acc[o].y += __shfl_xor(acc[o].y, 16);
        acc[o].z += __shfl_xor(acc[o].z, 16); acc[o].w += __shfl_xor(acc[o].w, 16);
        acc[o].x += __shfl_xor(acc[o].x, 32); acc[o].y += __shfl_xor(acc[o].y, 32);
        acc[o].z += __shfl_xor(acc[o].z, 32); acc[o].w += __shfl_xor(acc[o].w, 32);
    }
    if (lane < 16) {
        #pragma unroll
        for (int o = 0; o < O_N; ++o) s_red[wid][lane][o] = acc[o];
    }
    __syncthreads();

    // ---- cross-wave reduce + epilogue: 112 = 16 px4 x 7 outputs ----
    if (tid < 16 * O_N) {
        const int p2 = tid & 15;
        const int o  = tid >> 4;
        const float4 s0 = s_red[0][p2][o];
        const float4 s1 = s_red[1][p2][o];
        const float4 s2 = s_red[2][p2][o];
        const float4 s3 = s_red[3][p2][o];
        float4 zv;
        zv.x = s0.x + s1.x + s2.x + s3.x;
        zv.y = s0.y + s1.y + s2.y + s3.y;
        zv.z = s0.z + s1.z + s2.z + s3.z;
        zv.w = s0.w + s1.w + s2.w + s3.w;
        const float bo = b[o];
        const size_t ob = (size_t)(a * O_N + o) * P4_N + tile * 16 + p2;
        reinterpret_cast<float4*>(z)[ob] = zv;
        float4 sv;
        sv.x = sigmoidf_(zv.x + bo);
        sv.y = sigmoidf_(zv.y + bo);
        sv.z = sigmoidf_(zv.z + bo);
        sv.w = sigmoidf_(zv.w + bo);
        reinterpret_cast<float4*>(ssolo)[ob] = sv;
    }
}

// ---------------------------------------------------------------------------
// Aggregation: per ego i, pixel p: saggr = sigmoid(b + sum_j adj[i,j]!=0 ?
//              zero-padded-bilinear(z[j], rel[i,j] @ [u,v,1]) : 0)
// z planes total 1.9 MB — L2-resident gathers. 1080 blocks x 64.
// ---------------------------------------------------------------------------
__launch_bounds__(64)
__global__ void k_aggr(const float* __restrict__ z, const float* __restrict__ rel,
                       const int* __restrict__ adj, const float* __restrict__ b,
                       float* __restrict__ saggr)
{
    const int i = blockIdx.x / 135;
    const int p = (blockIdx.x - i * 135) * 64 + threadIdx.x;
    const int vy = p / W_N, ux = p - vy * W_N;
    const float fu = (float)ux, fv = (float)vy;

    float acc[O_N];
    #pragma unroll
    for (int o = 0; o < O_N; ++o) acc[o] = b[o];

    for (int j = 0; j < A_N; ++j) {
        if (adj[i * A_N + j] == 0) continue;
        const float* M = rel + (i * A_N + j) * 6;
        float sx = M[0] * fu + M[1] * fv + M[2];
        float sy = M[3] * fu + M[4] * fv + M[5];
        if (!(sx > -1.0f && sx < (float)W_N && sy > -1.0f && sy < (float)H_N)) continue;
        float x0f = floorf(sx), y0f = floorf(sy);
        float wx = sx - x0f, wy = sy - y0f;
        int x0 = (int)x0f, y0 = (int)y0f;
        int x1 = x0 + 1,  y1 = y0 + 1;
        float w00 = (1.0f - wy) * (1.0f - wx), w01 = (1.0f - wy) * wx;
        float w10 = wy * (1.0f - wx),          w11 = wy * wx;
        if (x0 < 0)    { w00 = 0.0f; w10 = 0.0f; x0 = 0; }
        if (x1 >= W_N) { w01 = 0.0f; w11 = 0.0f; x1 = W_N - 1; }
        if (y0 < 0)    { w00 = 0.0f; w01 = 0.0f; y0 = 0; }
        if (y1 >= H_N) { w10 = 0.0f; w11 = 0.0f; y1 = H_N - 1; }
        const int i00 = y0 * W_N + x0, i01 = y0 * W_N + x1;
        const int i10 = y1 * W_N + x0, i11 = y1 * W_N + x1;
        const float* zj = z + j * O_N * P_N;
        #pragma unroll
        for (int o = 0; o < O_N; ++o) {
            const float* zp = zj + o * P_N;
            acc[o] += w00 * zp[i00] + w01 * zp[i01] + w10 * zp[i10] + w11 * zp[i11];
        }
    }
    const int ob = i * O_N * P_N + p;
    #pragma unroll
    for (int o = 0; o < O_N; ++o) saggr[ob + o * P_N] = sigmoidf_(acc[o]);
}

// ---------------------------------------------------------------------------
// Upsample: align_corners=True bilinear 80x108 -> 256x256, f32 out.
// 4 px/thread -> float4 stores; 7168 blocks x 256 exact.
// Output layout: [solo(8,7,256,256), aggr(8,7,256,256)] flat f32.
// ---------------------------------------------------------------------------
__launch_bounds__(256)
__global__ void k_upsample(const float* __restrict__ ssolo, const float* __restrict__ saggr,
                           float* __restrict__ out)
{
    const int idx = blockIdx.x * 256 + threadIdx.x;   // quad index
    int k = idx;
    const int oxq = k & 63;   k >>= 6;
    const int oy  = k & 255;  k >>= 8;
    const int o   = k % O_N;  k /= O_N;
    const int a   = k & 7;    k >>= 3;
    const int t   = k;        // 0 = solo, 1 = aggr

    const float* src = (t == 0 ? ssolo : saggr) + (a * O_N + o) * P_N;
    float syf = (float)oy * (79.0f / 255.0f);
    int y0 = (int)syf; y0 = min(y0, H_N - 2);
    float wy = syf - (float)y0;
    const float* r0 = src + y0 * W_N;
    const float* r1 = r0 + W_N;

    float res[4];
    #pragma unroll
    for (int q = 0; q < 4; ++q) {
        int ox = oxq * 4 + q;
        float sxf = (float)ox * (107.0f / 255.0f);
        int x0 = (int)sxf; x0 = min(x0, W_N - 2);
        float wx = sxf - (float)x0;
        float c0 = r0[x0]     * (1.0f - wy) + r1[x0]     * wy;
        float c1 = r0[x0 + 1] * (1.0f - wy) + r1[x0 + 1] * wy;
        res[q] = c0 * (1.0f - wx) + c1 * wx;
    }
    *reinterpret_cast<float4*>(out + (size_t)idx * 4) =
        make_float4(res[0], res[1], res[2], res[3]);
}

// ---------------------------------------------------------------------------
extern "C" void kernel_launch(void* const* d_in, const int* in_sizes, int n_in,
                              void* d_out, int out_size, void* d_ws, size_t ws_size,
                              hipStream_t stream)
{
    (void)in_sizes; (void)n_in; (void)out_size; (void)ws_size;
    const float* x    = (const float*)d_in[0];
    const float* rel  = (const float*)d_in[1];
    const int*   adj  = (const int*)d_in[2];
    const float* cmsk = (const float*)d_in[3];
    const float* wcls = (const float*)d_in[4];
    const float* bcls = (const float*)d_in[5];
    float* out = (float*)d_out;   // reference output dtype is float32

    float* ws    = (float*)d_ws;
    float* z     = ws;                          // 8*7*8640 = 483,840 f32
    float* ssolo = z     + A_N * O_N * P_N;
    float* saggr = ssolo + A_N * O_N * P_N;     // total ~5.8 MB

    k_conv    <<<A_N * BPA, 256, 0, stream>>>(x, cmsk, wcls, bcls, z, ssolo);
    k_aggr    <<<1080, 64, 0, stream>>>(z, rel, adj, bcls, saggr);
    k_upsample<<<7168, 256, 0, stream>>>(ssolo, saggr, out);
}